// Round 5
// baseline (627.573 us; speedup 1.0000x reference)
//
#include <hip/hip_runtime.h>

static constexpr int NN = 50000;   // nodes
static constexpr int NE = 800000;  // edges
static constexpr int NBLK = (NN + 255) / 256;  // 196 scan blocks
// D = 128 features, hard-coded throughout.

__device__ __forceinline__ float clip100(float v) { return fminf(fmaxf(v, -100.f), 100.f); }
__device__ __forceinline__ float4 f4fma(float a, float4 w, float4 c) {
    c.x = fmaf(a, w.x, c.x);
    c.y = fmaf(a, w.y, c.y);
    c.z = fmaf(a, w.z, c.z);
    c.w = fmaf(a, w.w, c.w);
    return c;
}
__device__ __forceinline__ float4 f4add(float4 a, float4 b) {
    return make_float4(a.x + b.x, a.y + b.y, a.z + b.z, a.w + b.w);
}

// ---------------- CSR build ----------------
__global__ __launch_bounds__(256) void k_zero(int* __restrict__ cnt) {
    int i = blockIdx.x * 256 + threadIdx.x;
    if (i < NN) cnt[i] = 0;
}

__global__ __launch_bounds__(256) void k_hist(const int* __restrict__ idx,
                                              int* __restrict__ cnt) {
    int e = blockIdx.x * 256 + threadIdx.x;
    if (e < NE) atomicAdd(&cnt[idx[NE + e]], 1);
}

// per-block sums of cnt (coalesced)
__global__ __launch_bounds__(256) void k_bsum(const int* __restrict__ cnt,
                                              int* __restrict__ bsum) {
    __shared__ int ls[256];
    const int t = threadIdx.x;
    const int i = blockIdx.x * 256 + t;
    ls[t] = (i < NN) ? cnt[i] : 0;
    __syncthreads();
    for (int off = 128; off > 0; off >>= 1) {
        if (t < off) ls[t] += ls[t + off];
        __syncthreads();
    }
    if (t == 0) bsum[blockIdx.x] = ls[0];
}

// single block: exclusive scan of the NBLK partials -> bbase; rowptr[NN]=NE
__global__ __launch_bounds__(256) void k_scanb(const int* __restrict__ bsum,
                                               int* __restrict__ bbase,
                                               int* __restrict__ rowptr) {
    __shared__ int ls[256];
    const int t = threadIdx.x;
    ls[t] = (t < NBLK) ? bsum[t] : 0;
    __syncthreads();
    for (int off = 1; off < 256; off <<= 1) {
        const int add = (t >= off) ? ls[t - off] : 0;
        __syncthreads();
        ls[t] += add;
        __syncthreads();
    }
    if (t < NBLK) bbase[t] = (t == 0) ? 0 : ls[t - 1];
    if (t == 0) rowptr[NN] = NE;
}

// in-block exclusive scan + block base; writes rowptr, fill cursor, dinv
__global__ __launch_bounds__(256) void k_scan2(int* __restrict__ cnt,
                                               const int* __restrict__ bbase,
                                               int* __restrict__ rowptr,
                                               float* __restrict__ dinv) {
    __shared__ int ls[256];
    const int t = threadIdx.x;
    const int i = blockIdx.x * 256 + t;
    const int c = (i < NN) ? cnt[i] : 0;
    ls[t] = c;
    __syncthreads();
    for (int off = 1; off < 256; off <<= 1) {
        const int add = (t >= off) ? ls[t - off] : 0;
        __syncthreads();
        ls[t] += add;
        __syncthreads();
    }
    if (i < NN) {
        const int excl = bbase[blockIdx.x] + ls[t] - c;
        rowptr[i] = excl;
        cnt[i] = excl;  // fill cursor starts at row begin
        dinv[i] = rsqrtf(1.f + (float)c);
    }
}

__global__ __launch_bounds__(256) void k_fill(const int* __restrict__ idx,
                                              int* __restrict__ cur,
                                              int* __restrict__ esrc) {
    int e = blockIdx.x * 256 + threadIdx.x;
    if (e >= NE) return;
    const int s = idx[e];
    const int d = idx[NE + e];
    const int pos = atomicAdd(&cur[d], 1);
    esrc[pos] = s;
}

// ---------------- GEMM: C[n][j] = sum_k A[n][k] * W[k][j] ----------------
// 32-row tiles, thread = 2 rows x 8 cols (16 fp32 acc). W (64KB) + padded A
// tile (16.5KB) in LDS -> 2 blocks/CU. Per 4 k-steps: 10 ds_read_b128 vs
// 128 VALU-cyc of FMA -> VALU-bound.
// GATE epilogue: out = H * sigmoid(acc + Cprev + bg)  (fuses final gate).
template <bool CLIP, bool ACC, bool GATE>
__global__ __launch_bounds__(256) void k_gemm32(const float* __restrict__ A,
                                                const float* __restrict__ W,
                                                float* __restrict__ C, int ntiles,
                                                const float* __restrict__ H,
                                                const float* __restrict__ bg,
                                                float* __restrict__ out) {
    __shared__ float wf[128 * 128];
    __shared__ float af[32 * 132];  // row stride 132: spreads A-read banks
    const int tid = threadIdx.x;

    {
        const float4* __restrict__ W4 = (const float4*)W;
        float4* wf4w = (float4*)wf;
#pragma unroll
        for (int i = 0; i < 16; ++i) wf4w[tid + 256 * i] = W4[tid + 256 * i];
    }
    __syncthreads();

    const int cg = tid & 15;   // col group: cols cg*8 .. cg*8+7
    const int rg = tid >> 4;   // row pair: rows rg*2, rg*2+1
    const int r0 = rg * 2, r1 = r0 + 1;
    const float4* __restrict__ af4 = (const float4*)af;
    const float4* __restrict__ wf4 = (const float4*)wf;
    float4* __restrict__ C4 = (float4*)C;

    float4 bg0, bg1;
    if (GATE) {
        bg0 = ((const float4*)bg)[cg * 2];
        bg1 = ((const float4*)bg)[cg * 2 + 1];
    }

    for (int tile = blockIdx.x; tile < ntiles; tile += gridDim.x) {
        const int row0 = tile * 32;
        // stage A tile (guarded, zero-fill past NN)
        {
            const float4* __restrict__ A4 = (const float4*)A;
            float4* __restrict__ af4w = (float4*)af;
#pragma unroll
            for (int i = 0; i < 4; ++i) {
                const int idx = tid + 256 * i;  // 0..1023
                const int r = idx >> 5, c4 = idx & 31;
                float4 v = make_float4(0.f, 0.f, 0.f, 0.f);
                if (row0 + r < NN) {
                    v = A4[(long)(row0 + r) * 32 + c4];
                    if (CLIP) {
                        v.x = clip100(v.x); v.y = clip100(v.y);
                        v.z = clip100(v.z); v.w = clip100(v.w);
                    }
                }
                af4w[r * 33 + c4] = v;
            }
        }
        __syncthreads();

        float4 a00 = make_float4(0.f, 0.f, 0.f, 0.f), a01 = a00, a10 = a00, a11 = a00;

#pragma unroll 8
        for (int k4 = 0; k4 < 32; ++k4) {
            const float4 av0 = af4[r0 * 33 + k4];
            const float4 av1 = af4[r1 * 33 + k4];
            const int kb = k4 * 4;
#pragma unroll
            for (int kk = 0; kk < 4; ++kk) {
                const float4 w0 = wf4[(kb + kk) * 32 + cg * 2];
                const float4 w1 = wf4[(kb + kk) * 32 + cg * 2 + 1];
                const float a0 = ((const float*)&av0)[kk];
                const float a1 = ((const float*)&av1)[kk];
                a00 = f4fma(a0, w0, a00);
                a01 = f4fma(a0, w1, a01);
                a10 = f4fma(a1, w0, a10);
                a11 = f4fma(a1, w1, a11);
            }
        }

        const long o0 = (long)(row0 + r0) * 32 + cg * 2;
        const long o1 = (long)(row0 + r1) * 32 + cg * 2;
        const bool v0 = (row0 + r0) < NN;
        const bool v1 = (row0 + r1) < NN;

        if (!GATE) {
            if (ACC) {
                if (v0) { a00 = f4add(a00, C4[o0]); a01 = f4add(a01, C4[o0 + 1]); }
                if (v1) { a10 = f4add(a10, C4[o1]); a11 = f4add(a11, C4[o1 + 1]); }
            }
            if (v0) { C4[o0] = a00; C4[o0 + 1] = a01; }
            if (v1) { C4[o1] = a10; C4[o1 + 1] = a11; }
        } else {
            float4* __restrict__ O4 = (float4*)out;
            const float4* __restrict__ H4 = (const float4*)H;
            if (v0) {
                float4 g0 = f4add(f4add(a00, C4[o0]), bg0);
                float4 g1 = f4add(f4add(a01, C4[o0 + 1]), bg1);
                const float4 h0 = H4[o0], h1 = H4[o0 + 1];
                float4 r;
                r.x = h0.x / (1.f + __expf(-g0.x)); r.y = h0.y / (1.f + __expf(-g0.y));
                r.z = h0.z / (1.f + __expf(-g0.z)); r.w = h0.w / (1.f + __expf(-g0.w));
                O4[o0] = r;
                r.x = h1.x / (1.f + __expf(-g1.x)); r.y = h1.y / (1.f + __expf(-g1.y));
                r.z = h1.z / (1.f + __expf(-g1.z)); r.w = h1.w / (1.f + __expf(-g1.w));
                O4[o0 + 1] = r;
            }
            if (v1) {
                float4 g0 = f4add(f4add(a10, C4[o1]), bg0);
                float4 g1 = f4add(f4add(a11, C4[o1 + 1]), bg1);
                const float4 h0 = H4[o1], h1 = H4[o1 + 1];
                float4 r;
                r.x = h0.x / (1.f + __expf(-g0.x)); r.y = h0.y / (1.f + __expf(-g0.y));
                r.z = h0.z / (1.f + __expf(-g0.z)); r.w = h0.w / (1.f + __expf(-g0.w));
                O4[o1] = r;
                r.x = h1.x / (1.f + __expf(-g1.x)); r.y = h1.y / (1.f + __expf(-g1.y));
                r.z = h1.z / (1.f + __expf(-g1.z)); r.w = h1.w / (1.f + __expf(-g1.w));
                O4[o1 + 1] = r;
            }
        }
        __syncthreads();
    }
}

// ---------------- fused aggregation ----------------
// One wave (64 lanes) per node d; lane owns cols [2*lane, 2*lane+1].
// B[d] = relu( sum_{e: dst=d} A[src_e]*dinv[s]*dinv[d] + A[d]*dinv[d]^2 + bias )
//        (+ clip(x[d]) if RES)
template <bool RES>
__global__ __launch_bounds__(256) void k_aggr(const float* __restrict__ A,
                                              float* __restrict__ B,
                                              const int* __restrict__ rowptr,
                                              const int* __restrict__ esrc,
                                              const float* __restrict__ dinv,
                                              const float* __restrict__ bias,
                                              const float* __restrict__ x) {
    const int d = (blockIdx.x * 256 + threadIdx.x) >> 6;  // wave id == node
    if (d >= NN) return;
    const int lane = threadIdx.x & 63;
    const float2* __restrict__ A2 = (const float2*)A;

    const float dd = dinv[d];
    float2 acc = A2[(long)d * 64 + lane];
    const float sl = dd * dd;
    acc.x *= sl;
    acc.y *= sl;

    const int beg = rowptr[d];
    const int end = rowptr[d + 1];
#pragma unroll 2
    for (int i = beg; i < end; ++i) {
        const int s = esrc[i];
        const float w = dinv[s] * dd;
        const float2 v = A2[(long)s * 64 + lane];
        acc.x = fmaf(v.x, w, acc.x);
        acc.y = fmaf(v.y, w, acc.y);
    }

    const float2 bv = ((const float2*)bias)[lane];
    acc.x = fmaxf(acc.x + bv.x, 0.f);
    acc.y = fmaxf(acc.y + bv.y, 0.f);
    if (RES) {
        const float2 xv = ((const float2*)x)[(long)d * 64 + lane];
        acc.x += clip100(xv.x);
        acc.y += clip100(xv.y);
    }
    ((float2*)B)[(long)d * 64 + lane] = acc;
}

// ---------------- launch ----------------
extern "C" void kernel_launch(void* const* d_in, const int* in_sizes, int n_in,
                              void* d_out, int out_size, void* d_ws, size_t ws_size,
                              hipStream_t stream) {
    const float* x  = (const float*)d_in[0];
    const int*  eix = (const int*)d_in[1];
    const float* W1 = (const float*)d_in[2];
    const float* b1 = (const float*)d_in[3];
    const float* W2 = (const float*)d_in[4];
    const float* b2 = (const float*)d_in[5];
    const float* Wg = (const float*)d_in[6];
    const float* bg = (const float*)d_in[7];
    float* out = (float*)d_out;

    char* ws = (char*)d_ws;
    const size_t NB = (size_t)NN * 128 * sizeof(float);  // 25.6 MB
    float* bufA   = (float*)ws;                          // GEMM outputs / gate acc
    int*   cnt    = (int*)(ws + NB);                     // histogram -> fill cursor
    int*   rowptr = (int*)(ws + NB + 1 * 200704);        // NN+1 ints (padded region)
    float* dinv   = (float*)(ws + NB + 2 * 200704);
    int*   bsum   = (int*)(ws + NB + 3 * 200704);        // NBLK ints
    int*   bbase  = (int*)(ws + NB + 3 * 200704 + 4096); // NBLK ints
    int*   esrc   = (int*)(ws + NB + 4 * 200704);        // NE ints
    float* bufB   = out;                                 // H buffer aliases d_out

    const int ntiles = (NN + 31) / 32;  // 1563
    const int ggrid = 522;              // <=3 tiles per persistent block
    dim3 blk(256);

    // CSR + normalization (decomposed parallel scan)
    k_zero<<<NBLK, blk, 0, stream>>>(cnt);
    k_hist<<<(NE + 255) / 256, blk, 0, stream>>>(eix, cnt);
    k_bsum<<<NBLK, blk, 0, stream>>>(cnt, bsum);
    k_scanb<<<1, blk, 0, stream>>>(bsum, bbase, rowptr);
    k_scan2<<<NBLK, blk, 0, stream>>>(cnt, bbase, rowptr, dinv);
    k_fill<<<(NE + 255) / 256, blk, 0, stream>>>(eix, cnt, esrc);

    // layer 1: t = clip(x) @ W1 ; h1 = relu(agg(t) + b1)   (h1 in bufB)
    k_gemm32<true, false, false><<<ggrid, blk, 0, stream>>>(x, W1, bufA, ntiles,
                                                            nullptr, nullptr, nullptr);
    k_aggr<false><<<(NN * 64 + 255) / 256, blk, 0, stream>>>(bufA, bufB, rowptr, esrc,
                                                             dinv, b1, nullptr);

    // layer 2: t = h1 @ W2 ; h = relu(agg(t) + b2) + clip(x)   (h in bufB)
    k_gemm32<false, false, false><<<ggrid, blk, 0, stream>>>(bufB, W2, bufA, ntiles,
                                                             nullptr, nullptr, nullptr);
    k_aggr<true><<<(NN * 64 + 255) / 256, blk, 0, stream>>>(bufA, bufB, rowptr, esrc,
                                                            dinv, b2, x);

    // gate: G = h @ Wg[0:128] + clip(x) @ Wg[128:256] ; out = h * sigmoid(G + bg)
    // (second GEMM fuses ACC + sigmoid + multiply-by-H, writes out in place)
    k_gemm32<false, false, false><<<ggrid, blk, 0, stream>>>(bufB, Wg, bufA, ntiles,
                                                             nullptr, nullptr, nullptr);
    k_gemm32<true, true, true><<<ggrid, blk, 0, stream>>>(x, Wg + 128 * 128, bufA, ntiles,
                                                          bufB, bg, out);
}

// Round 6
// 404.485 us; speedup vs baseline: 1.5515x; 1.5515x over previous
//
#include <hip/hip_runtime.h>
#include <hip/hip_bf16.h>

using short8 = __attribute__((ext_vector_type(8))) short;
using f32x4  = __attribute__((ext_vector_type(4))) float;

static constexpr int NN = 50000;   // nodes
static constexpr int NE = 800000;  // edges
static constexpr int NBLK = (NN + 255) / 256;  // 196 scan blocks
static constexpr int MPAD = 50048; // 782 * 64 padded rows for bf16 activations

__device__ __forceinline__ float clip100(float v) { return fminf(fmaxf(v, -100.f), 100.f); }
__device__ __forceinline__ unsigned short f2b(float v) {
    __hip_bfloat16 h = __float2bfloat16(v);
    return *reinterpret_cast<unsigned short*>(&h);
}

// ---------------- CSR build ----------------
__global__ __launch_bounds__(256) void k_zero(int* __restrict__ cnt) {
    int i = blockIdx.x * 256 + threadIdx.x;
    if (i < NN) cnt[i] = 0;
}

__global__ __launch_bounds__(256) void k_hist(const int* __restrict__ idx,
                                              int* __restrict__ cnt) {
    int e = blockIdx.x * 256 + threadIdx.x;
    if (e < NE) atomicAdd(&cnt[idx[NE + e]], 1);
}

__global__ __launch_bounds__(256) void k_bsum(const int* __restrict__ cnt,
                                              int* __restrict__ bsum) {
    __shared__ int ls[256];
    const int t = threadIdx.x;
    const int i = blockIdx.x * 256 + t;
    ls[t] = (i < NN) ? cnt[i] : 0;
    __syncthreads();
    for (int off = 128; off > 0; off >>= 1) {
        if (t < off) ls[t] += ls[t + off];
        __syncthreads();
    }
    if (t == 0) bsum[blockIdx.x] = ls[0];
}

__global__ __launch_bounds__(256) void k_scanb(const int* __restrict__ bsum,
                                               int* __restrict__ bbase,
                                               int* __restrict__ rowptr) {
    __shared__ int ls[256];
    const int t = threadIdx.x;
    ls[t] = (t < NBLK) ? bsum[t] : 0;
    __syncthreads();
    for (int off = 1; off < 256; off <<= 1) {
        const int add = (t >= off) ? ls[t - off] : 0;
        __syncthreads();
        ls[t] += add;
        __syncthreads();
    }
    if (t < NBLK) bbase[t] = (t == 0) ? 0 : ls[t - 1];
    if (t == 0) rowptr[NN] = NE;
}

__global__ __launch_bounds__(256) void k_scan2(int* __restrict__ cnt,
                                               const int* __restrict__ bbase,
                                               int* __restrict__ rowptr,
                                               float* __restrict__ dinv) {
    __shared__ int ls[256];
    const int t = threadIdx.x;
    const int i = blockIdx.x * 256 + t;
    const int c = (i < NN) ? cnt[i] : 0;
    ls[t] = c;
    __syncthreads();
    for (int off = 1; off < 256; off <<= 1) {
        const int add = (t >= off) ? ls[t - off] : 0;
        __syncthreads();
        ls[t] += add;
        __syncthreads();
    }
    if (i < NN) {
        const int excl = bbase[blockIdx.x] + ls[t] - c;
        rowptr[i] = excl;
        cnt[i] = excl;  // fill cursor
        dinv[i] = rsqrtf(1.f + (float)c);
    }
}

__global__ __launch_bounds__(256) void k_fill(const int* __restrict__ idx,
                                              int* __restrict__ cur,
                                              int* __restrict__ esrc) {
    int e = blockIdx.x * 256 + threadIdx.x;
    if (e >= NE) return;
    const int s = idx[e];
    const int d = idx[NE + e];
    const int pos = atomicAdd(&cur[d], 1);
    esrc[pos] = s;
}

// ---------------- weight transpose + bf16 convert ----------------
// Wt1[n][k]=W1[k][n], Wt2 likewise (128x128); Wgt[n][k]=Wg[k][n] (n<128, k<256)
__global__ __launch_bounds__(256) void k_cvtw(const float* __restrict__ W1,
                                              const float* __restrict__ W2,
                                              const float* __restrict__ Wg,
                                              unsigned short* __restrict__ Wt1,
                                              unsigned short* __restrict__ Wt2,
                                              unsigned short* __restrict__ Wgt) {
    const int i = blockIdx.x * 256 + threadIdx.x;  // 0..65535
    if (i < 16384) {
        const int n = i >> 7, k = i & 127;
        Wt1[i] = f2b(W1[k * 128 + n]);
    } else if (i < 32768) {
        const int j = i - 16384;
        const int n = j >> 7, k = j & 127;
        Wt2[j] = f2b(W2[k * 128 + n]);
    } else {
        const int j = i - 32768;
        const int n = j >> 8, k = j & 255;
        Wgt[j] = f2b(Wg[k * 128 + n]);
    }
}

// ---------------- MFMA GEMM: C[m][n] = A[m][:] @ W[:][n] ----------------
// A-side: optional bf16 activations Ab (rows padded to MPAD) for k in [0,128),
// optional fp32 source Af (clip applied, row-guarded) for the next 128 k's.
// Wt is bf16 [128][K] n-major (row n holds W[k][n] for all k). No LDS.
// Wave = 16 rows x 128 cols (8 n-tiles); block = 4 waves = 64 rows.
// Fragment layouts (m89/m120-verified): A[m=lane&15][k=quad*8+j],
// B[k=quad*8+j][n=lane&15], D col=lane&15, row=quad*4+reg.
// GATE: out[row][col] = H[row][col] * sigmoid(acc + bg[col])  (in-place on H).
template <bool AB16, bool AF32, bool GATE>
__global__ __launch_bounds__(256) void k_mfma(const unsigned short* __restrict__ Ab,
                                              const float* __restrict__ Af,
                                              const unsigned short* __restrict__ Wt,
                                              float* __restrict__ C,
                                              const float* __restrict__ bg,
                                              float* __restrict__ H) {
    constexpr int K = (AB16 ? 128 : 0) + (AF32 ? 128 : 0);
    const int wv = threadIdx.x >> 6;
    const int ln = threadIdx.x & 63;
    const int l16 = ln & 15;
    const int qd = ln >> 4;
    const int rowb = blockIdx.x * 64 + wv * 16;
    const long arow = rowb + l16;
    const int kq = qd * 8;

    f32x4 acc[8];
#pragma unroll
    for (int i = 0; i < 8; ++i) acc[i] = (f32x4){0.f, 0.f, 0.f, 0.f};

    if (AB16) {
        const unsigned short* ap = Ab + arow * 128 + kq;
#pragma unroll
        for (int kc = 0; kc < 4; ++kc) {
            const short8 a = *(const short8*)(ap + kc * 32);
#pragma unroll
            for (int nt = 0; nt < 8; ++nt) {
                const short8 b = *(const short8*)(Wt + (long)(nt * 16 + l16) * K + kc * 32 + kq);
                acc[nt] = __builtin_amdgcn_mfma_f32_16x16x32_bf16(a, b, acc[nt], 0, 0, 0);
            }
        }
    }
    if (AF32) {
        constexpr int k0 = AB16 ? 128 : 0;
        const bool valid = arow < NN;
        const float* fp = Af + arow * 128 + kq;
#pragma unroll
        for (int kc = 0; kc < 4; ++kc) {
            short8 a = (short8){0, 0, 0, 0, 0, 0, 0, 0};
            if (valid) {
                const float4 f0 = *(const float4*)(fp + kc * 32);
                const float4 f1 = *(const float4*)(fp + kc * 32 + 4);
                a[0] = (short)f2b(clip100(f0.x));
                a[1] = (short)f2b(clip100(f0.y));
                a[2] = (short)f2b(clip100(f0.z));
                a[3] = (short)f2b(clip100(f0.w));
                a[4] = (short)f2b(clip100(f1.x));
                a[5] = (short)f2b(clip100(f1.y));
                a[6] = (short)f2b(clip100(f1.z));
                a[7] = (short)f2b(clip100(f1.w));
            }
#pragma unroll
            for (int nt = 0; nt < 8; ++nt) {
                const short8 b = *(const short8*)(Wt + (long)(nt * 16 + l16) * K + k0 + kc * 32 + kq);
                acc[nt] = __builtin_amdgcn_mfma_f32_16x16x32_bf16(a, b, acc[nt], 0, 0, 0);
            }
        }
    }

    const int r0 = rowb + qd * 4;
    if (!GATE) {
#pragma unroll
        for (int nt = 0; nt < 8; ++nt) {
            const int col = nt * 16 + l16;
#pragma unroll
            for (int r = 0; r < 4; ++r) {
                const int row = r0 + r;
                if (row < NN) C[(long)row * 128 + col] = acc[nt][r];
            }
        }
    } else {
#pragma unroll
        for (int nt = 0; nt < 8; ++nt) {
            const int col = nt * 16 + l16;
            const float bgv = bg[col];
#pragma unroll
            for (int r = 0; r < 4; ++r) {
                const int row = r0 + r;
                if (row < NN) {
                    const float g = 1.f / (1.f + __expf(-(acc[nt][r] + bgv)));
                    H[(long)row * 128 + col] *= g;
                }
            }
        }
    }
}

// ---------------- fused aggregation ----------------
// One wave per node d; lane owns cols [2*lane, 2*lane+1].
// acc = relu( sum_{e: dst=d} A[src]*dinv[s]*dinv[d] + A[d]*dinv[d]^2 + bias )
//       (+ clip(x[d]) if RES).  Writes bf16 Bb always; fp32 Bf if WF32.
template <bool RES, bool WF32>
__global__ __launch_bounds__(256) void k_aggr(const float* __restrict__ A,
                                              float* __restrict__ Bf,
                                              unsigned short* __restrict__ Bb,
                                              const int* __restrict__ rowptr,
                                              const int* __restrict__ esrc,
                                              const float* __restrict__ dinv,
                                              const float* __restrict__ bias,
                                              const float* __restrict__ x) {
    const int d = (blockIdx.x * 256 + threadIdx.x) >> 6;
    if (d >= NN) return;
    const int lane = threadIdx.x & 63;
    const float2* __restrict__ A2 = (const float2*)A;

    const float dd = dinv[d];
    float2 acc = A2[(long)d * 64 + lane];
    const float sl = dd * dd;
    acc.x *= sl;
    acc.y *= sl;

    const int beg = rowptr[d];
    const int end = rowptr[d + 1];
#pragma unroll 2
    for (int i = beg; i < end; ++i) {
        const int s = esrc[i];
        const float w = dinv[s] * dd;
        const float2 v = A2[(long)s * 64 + lane];
        acc.x = fmaf(v.x, w, acc.x);
        acc.y = fmaf(v.y, w, acc.y);
    }

    const float2 bv = ((const float2*)bias)[lane];
    acc.x = fmaxf(acc.x + bv.x, 0.f);
    acc.y = fmaxf(acc.y + bv.y, 0.f);
    if (RES) {
        const float2 xv = ((const float2*)x)[(long)d * 64 + lane];
        acc.x += clip100(xv.x);
        acc.y += clip100(xv.y);
    }
    if (WF32) ((float2*)Bf)[(long)d * 64 + lane] = acc;
    const unsigned int pack = (unsigned int)f2b(acc.x) | ((unsigned int)f2b(acc.y) << 16);
    ((unsigned int*)Bb)[(long)d * 64 + lane] = pack;
}

// ---------------- launch ----------------
extern "C" void kernel_launch(void* const* d_in, const int* in_sizes, int n_in,
                              void* d_out, int out_size, void* d_ws, size_t ws_size,
                              hipStream_t stream) {
    const float* x  = (const float*)d_in[0];
    const int*  eix = (const int*)d_in[1];
    const float* W1 = (const float*)d_in[2];
    const float* b1 = (const float*)d_in[3];
    const float* W2 = (const float*)d_in[4];
    const float* b2 = (const float*)d_in[5];
    const float* Wg = (const float*)d_in[6];
    const float* bg = (const float*)d_in[7];
    float* out = (float*)d_out;

    char* ws = (char*)d_ws;
    float*          bufA = (float*)ws;                              // 25,600,000 B
    unsigned short* hb   = (unsigned short*)(ws + 25600000);        // 12,812,288 B
    unsigned short* Wt1  = (unsigned short*)(ws + 38412288);        // 32,768 B
    unsigned short* Wt2  = (unsigned short*)(ws + 38445056);        // 32,768 B
    unsigned short* Wgt  = (unsigned short*)(ws + 38477824);        // 65,536 B
    int*   cnt    = (int*)(ws + 38543360);                          // 200,704 B
    int*   rowptr = (int*)(ws + 38744064);                          // 200,704 B
    float* dinv   = (float*)(ws + 38944768);                        // 200,704 B
    int*   bsum   = (int*)(ws + 39145472);                          // 4,096 B
    int*   bbase  = (int*)(ws + 39149568);                          // 4,096 B
    int*   esrc   = (int*)(ws + 39153664);                          // 3,200,000 B

    const int ggrid = MPAD / 64;  // 782
    dim3 blk(256);

    // CSR + normalization + weight conversion
    k_zero<<<NBLK, blk, 0, stream>>>(cnt);
    k_hist<<<(NE + 255) / 256, blk, 0, stream>>>(eix, cnt);
    k_bsum<<<NBLK, blk, 0, stream>>>(cnt, bsum);
    k_scanb<<<1, blk, 0, stream>>>(bsum, bbase, rowptr);
    k_scan2<<<NBLK, blk, 0, stream>>>(cnt, bbase, rowptr, dinv);
    k_fill<<<(NE + 255) / 256, blk, 0, stream>>>(eix, cnt, esrc);
    k_cvtw<<<256, blk, 0, stream>>>(W1, W2, Wg, Wt1, Wt2, Wgt);

    // layer 1: t = clip(x) @ W1 (MFMA) ; h1b = bf16(relu(agg(t) + b1))
    k_mfma<false, true, false><<<ggrid, blk, 0, stream>>>(nullptr, x, Wt1, bufA,
                                                          nullptr, nullptr);
    k_aggr<false, false><<<(NN * 64 + 255) / 256, blk, 0, stream>>>(
        bufA, nullptr, hb, rowptr, esrc, dinv, b1, nullptr);

    // layer 2: t = h1b @ W2 ; h = relu(agg(t) + b2) + clip(x)  (fp32 -> out, bf16 -> hb)
    k_mfma<true, false, false><<<ggrid, blk, 0, stream>>>(hb, nullptr, Wt2, bufA,
                                                          nullptr, nullptr);
    k_aggr<true, true><<<(NN * 64 + 255) / 256, blk, 0, stream>>>(
        bufA, out, hb, rowptr, esrc, dinv, b2, x);

    // gate: G = [hb | clip(x)] @ Wgt (K=256) ; out = h * sigmoid(G + bg) in-place
    k_mfma<true, true, true><<<ggrid, blk, 0, stream>>>(hb, x, Wgt, nullptr, bg, out);
}

// Round 7
// 374.252 us; speedup vs baseline: 1.6769x; 1.0808x over previous
//
#include <hip/hip_runtime.h>
#include <hip/hip_bf16.h>

using short8 = __attribute__((ext_vector_type(8))) short;
using f32x4  = __attribute__((ext_vector_type(4))) float;

static constexpr int NN = 50000;   // nodes
static constexpr int NE = 800000;  // edges
static constexpr int NBLK = (NN + 255) / 256;  // 196 scan blocks
static constexpr int MPAD = 50048; // 782 * 64 padded rows for bf16 activations

__device__ __forceinline__ float clip100(float v) { return fminf(fmaxf(v, -100.f), 100.f); }
__device__ __forceinline__ unsigned short f2b(float v) {
    __hip_bfloat16 h = __float2bfloat16(v);
    return *reinterpret_cast<unsigned short*>(&h);
}

// ---------------- CSR build ----------------
__global__ __launch_bounds__(256) void k_hist(const int* __restrict__ idx,
                                              int* __restrict__ cnt) {
    int e = blockIdx.x * 256 + threadIdx.x;
    if (e < NE) atomicAdd(&cnt[idx[NE + e]], 1);
}

__global__ __launch_bounds__(256) void k_bsum(const int* __restrict__ cnt,
                                              int* __restrict__ bsum) {
    __shared__ int ls[256];
    const int t = threadIdx.x;
    const int i = blockIdx.x * 256 + t;
    ls[t] = (i < NN) ? cnt[i] : 0;
    __syncthreads();
    for (int off = 128; off > 0; off >>= 1) {
        if (t < off) ls[t] += ls[t + off];
        __syncthreads();
    }
    if (t == 0) bsum[blockIdx.x] = ls[0];
}

__global__ __launch_bounds__(256) void k_scanb(const int* __restrict__ bsum,
                                               int* __restrict__ bbase,
                                               int* __restrict__ rowptr) {
    __shared__ int ls[256];
    const int t = threadIdx.x;
    ls[t] = (t < NBLK) ? bsum[t] : 0;
    __syncthreads();
    for (int off = 1; off < 256; off <<= 1) {
        const int add = (t >= off) ? ls[t - off] : 0;
        __syncthreads();
        ls[t] += add;
        __syncthreads();
    }
    if (t < NBLK) bbase[t] = (t == 0) ? 0 : ls[t - 1];
    if (t == 0) rowptr[NN] = NE;
}

__global__ __launch_bounds__(256) void k_scan2(int* __restrict__ cnt,
                                               const int* __restrict__ bbase,
                                               int* __restrict__ rowptr,
                                               float* __restrict__ dinv) {
    __shared__ int ls[256];
    const int t = threadIdx.x;
    const int i = blockIdx.x * 256 + t;
    const int c = (i < NN) ? cnt[i] : 0;
    ls[t] = c;
    __syncthreads();
    for (int off = 1; off < 256; off <<= 1) {
        const int add = (t >= off) ? ls[t - off] : 0;
        __syncthreads();
        ls[t] += add;
        __syncthreads();
    }
    if (i < NN) {
        const int excl = bbase[blockIdx.x] + ls[t] - c;
        rowptr[i] = excl;
        cnt[i] = excl;  // fill cursor
        dinv[i] = rsqrtf(1.f + (float)c);
    }
}

__global__ __launch_bounds__(256) void k_fill(const int* __restrict__ idx,
                                              int* __restrict__ cur,
                                              int* __restrict__ esrc) {
    int e = blockIdx.x * 256 + threadIdx.x;
    if (e >= NE) return;
    const int s = idx[e];
    const int d = idx[NE + e];
    const int pos = atomicAdd(&cur[d], 1);
    esrc[pos] = s;
}

// ---------------- weight transpose + bf16 convert (+ cnt zero) ----------------
// Wt1[n][k]=W1[k][n], Wt2 likewise (128x128); Wgt[n][k]=Wg[k][n] (n<128, k<256)
__global__ __launch_bounds__(256) void k_cvtw(const float* __restrict__ W1,
                                              const float* __restrict__ W2,
                                              const float* __restrict__ Wg,
                                              unsigned short* __restrict__ Wt1,
                                              unsigned short* __restrict__ Wt2,
                                              unsigned short* __restrict__ Wgt,
                                              int* __restrict__ cnt) {
    const int i = blockIdx.x * 256 + threadIdx.x;  // 0..65535
    if (i < NN) cnt[i] = 0;
    if (i < 16384) {
        const int n = i >> 7, k = i & 127;
        Wt1[i] = f2b(W1[k * 128 + n]);
    } else if (i < 32768) {
        const int j = i - 16384;
        const int n = j >> 7, k = j & 127;
        Wt2[j] = f2b(W2[k * 128 + n]);
    } else {
        const int j = i - 32768;
        const int n = j >> 8, k = j & 255;
        Wgt[j] = f2b(Wg[k * 128 + n]);
    }
}

// ---------------- MFMA GEMM: C[m][n] = A[m][:] @ W[:][n] ----------------
// A-side: optional bf16 activations Ab (rows padded to MPAD) for k in [0,128),
// optional fp32 source Af (clip applied, row-guarded) for the next 128 k's.
// Wt is bf16 [128][K] n-major. No LDS; wave = 16 rows x 128 cols, block = 64 rows.
// !GATE epilogue: Cb[row][col] = bf16(acc * dinv[row])   (scaled message buffer)
//  GATE epilogue: H[row][col] *= sigmoid(acc + bg[col])  (in-place gate)
template <bool AB16, bool AF32, bool GATE>
__global__ __launch_bounds__(256) void k_mfma(const unsigned short* __restrict__ Ab,
                                              const float* __restrict__ Af,
                                              const unsigned short* __restrict__ Wt,
                                              unsigned short* __restrict__ Cb,
                                              const float* __restrict__ dinv,
                                              const float* __restrict__ bg,
                                              float* __restrict__ H) {
    constexpr int K = (AB16 ? 128 : 0) + (AF32 ? 128 : 0);
    const int wv = threadIdx.x >> 6;
    const int ln = threadIdx.x & 63;
    const int l16 = ln & 15;
    const int qd = ln >> 4;
    const int rowb = blockIdx.x * 64 + wv * 16;
    const long arow = rowb + l16;
    const int kq = qd * 8;

    f32x4 acc[8];
#pragma unroll
    for (int i = 0; i < 8; ++i) acc[i] = (f32x4){0.f, 0.f, 0.f, 0.f};

    if (AB16) {
        const unsigned short* ap = Ab + arow * 128 + kq;
#pragma unroll
        for (int kc = 0; kc < 4; ++kc) {
            const short8 a = *(const short8*)(ap + kc * 32);
#pragma unroll
            for (int nt = 0; nt < 8; ++nt) {
                const short8 b = *(const short8*)(Wt + (long)(nt * 16 + l16) * K + kc * 32 + kq);
                acc[nt] = __builtin_amdgcn_mfma_f32_16x16x32_bf16(a, b, acc[nt], 0, 0, 0);
            }
        }
    }
    if (AF32) {
        constexpr int k0 = AB16 ? 128 : 0;
        const bool valid = arow < NN;
        const float* fp = Af + arow * 128 + kq;
#pragma unroll
        for (int kc = 0; kc < 4; ++kc) {
            short8 a = (short8){0, 0, 0, 0, 0, 0, 0, 0};
            if (valid) {
                const float4 f0 = *(const float4*)(fp + kc * 32);
                const float4 f1 = *(const float4*)(fp + kc * 32 + 4);
                a[0] = (short)f2b(clip100(f0.x));
                a[1] = (short)f2b(clip100(f0.y));
                a[2] = (short)f2b(clip100(f0.z));
                a[3] = (short)f2b(clip100(f0.w));
                a[4] = (short)f2b(clip100(f1.x));
                a[5] = (short)f2b(clip100(f1.y));
                a[6] = (short)f2b(clip100(f1.z));
                a[7] = (short)f2b(clip100(f1.w));
            }
#pragma unroll
            for (int nt = 0; nt < 8; ++nt) {
                const short8 b = *(const short8*)(Wt + (long)(nt * 16 + l16) * K + k0 + kc * 32 + kq);
                acc[nt] = __builtin_amdgcn_mfma_f32_16x16x32_bf16(a, b, acc[nt], 0, 0, 0);
            }
        }
    }

    const int r0 = rowb + qd * 4;
    if (!GATE) {
#pragma unroll
        for (int r = 0; r < 4; ++r) {
            const int row = r0 + r;
            if (row < NN) {
                const float dv = dinv[row];
#pragma unroll
                for (int nt = 0; nt < 8; ++nt) {
                    const int col = nt * 16 + l16;
                    Cb[(long)row * 128 + col] = f2b(acc[nt][r] * dv);
                }
            }
        }
    } else {
#pragma unroll
        for (int nt = 0; nt < 8; ++nt) {
            const int col = nt * 16 + l16;
            const float bgv = bg[col];
#pragma unroll
            for (int r = 0; r < 4; ++r) {
                const int row = r0 + r;
                if (row < NN) {
                    const float g = 1.f / (1.f + __expf(-(acc[nt][r] + bgv)));
                    H[(long)row * 128 + col] *= g;
                }
            }
        }
    }
}

// ---------------- fused aggregation (bf16 scaled messages) ----------------
// One wave per node d; lane owns cols [2*lane, 2*lane+1] packed in one uint.
// acc = dinv[d] * ( sum_{e: dst=d} As[src] + As[d] )   [As already ×dinv[src]]
// B = relu(acc + bias) (+ clip(x[d]) if RES). fp32 accumulate throughout.
template <bool RES, bool WF32>
__global__ __launch_bounds__(256) void k_aggr(const unsigned int* __restrict__ As2,
                                              float* __restrict__ Bf,
                                              unsigned short* __restrict__ Bb,
                                              const int* __restrict__ rowptr,
                                              const int* __restrict__ esrc,
                                              const float* __restrict__ dinv,
                                              const float* __restrict__ bias,
                                              const float* __restrict__ x) {
    const int d = (blockIdx.x * 256 + threadIdx.x) >> 6;
    if (d >= NN) return;
    const int lane = threadIdx.x & 63;

    unsigned int u = As2[(long)d * 64 + lane];  // self term
    float2 acc;
    acc.x = __uint_as_float(u << 16);
    acc.y = __uint_as_float(u & 0xFFFF0000u);

    const int beg = rowptr[d];
    const int end = rowptr[d + 1];
#pragma unroll 2
    for (int i = beg; i < end; ++i) {
        const int s = esrc[i];
        const unsigned int v = As2[(long)s * 64 + lane];
        acc.x += __uint_as_float(v << 16);
        acc.y += __uint_as_float(v & 0xFFFF0000u);
    }

    const float dd = dinv[d];
    const float2 bv = ((const float2*)bias)[lane];
    acc.x = fmaxf(fmaf(acc.x, dd, bv.x), 0.f);
    acc.y = fmaxf(fmaf(acc.y, dd, bv.y), 0.f);
    if (RES) {
        const float2 xv = ((const float2*)x)[(long)d * 64 + lane];
        acc.x += clip100(xv.x);
        acc.y += clip100(xv.y);
    }
    if (WF32) ((float2*)Bf)[(long)d * 64 + lane] = acc;
    const unsigned int pack = (unsigned int)f2b(acc.x) | ((unsigned int)f2b(acc.y) << 16);
    ((unsigned int*)Bb)[(long)d * 64 + lane] = pack;
}

// ---------------- launch ----------------
extern "C" void kernel_launch(void* const* d_in, const int* in_sizes, int n_in,
                              void* d_out, int out_size, void* d_ws, size_t ws_size,
                              hipStream_t stream) {
    const float* x  = (const float*)d_in[0];
    const int*  eix = (const int*)d_in[1];
    const float* W1 = (const float*)d_in[2];
    const float* b1 = (const float*)d_in[3];
    const float* W2 = (const float*)d_in[4];
    const float* b2 = (const float*)d_in[5];
    const float* Wg = (const float*)d_in[6];
    const float* bg = (const float*)d_in[7];
    float* out = (float*)d_out;

    char* ws = (char*)d_ws;
    unsigned short* As   = (unsigned short*)ws;                     // 12,812,288 B
    unsigned short* hb   = (unsigned short*)(ws + 12812288);        // 12,812,288 B
    unsigned short* Wt1  = (unsigned short*)(ws + 25624576);        // 32,768 B
    unsigned short* Wt2  = (unsigned short*)(ws + 25657344);        // 32,768 B
    unsigned short* Wgt  = (unsigned short*)(ws + 25690112);        // 65,536 B
    int*   cnt    = (int*)(ws + 25755648);                          // 200,704 B
    int*   rowptr = (int*)(ws + 25956352);                          // 200,704 B
    float* dinv   = (float*)(ws + 26157056);                        // 200,704 B
    int*   bsum   = (int*)(ws + 26357760);                          // 4,096 B
    int*   bbase  = (int*)(ws + 26361856);                          // 4,096 B
    int*   esrc   = (int*)(ws + 26365952);                          // 3,200,000 B

    const int ggrid = MPAD / 64;  // 782
    dim3 blk(256);

    // weight conversion (also zeroes cnt), then CSR + normalization
    k_cvtw<<<256, blk, 0, stream>>>(W1, W2, Wg, Wt1, Wt2, Wgt, cnt);
    k_hist<<<(NE + 255) / 256, blk, 0, stream>>>(eix, cnt);
    k_bsum<<<NBLK, blk, 0, stream>>>(cnt, bsum);
    k_scanb<<<1, blk, 0, stream>>>(bsum, bbase, rowptr);
    k_scan2<<<NBLK, blk, 0, stream>>>(cnt, bbase, rowptr, dinv);
    k_fill<<<(NE + 255) / 256, blk, 0, stream>>>(eix, cnt, esrc);

    // layer 1: As = bf16((clip(x)@W1) * dinv) ; h1b = bf16(relu(dinv*ΣAs + b1))
    k_mfma<false, true, false><<<ggrid, blk, 0, stream>>>(nullptr, x, Wt1, As,
                                                          dinv, nullptr, nullptr);
    k_aggr<false, false><<<(NN * 64 + 255) / 256, blk, 0, stream>>>(
        (const unsigned int*)As, nullptr, hb, rowptr, esrc, dinv, b1, nullptr);

    // layer 2: As = bf16((h1b@W2) * dinv) ; h = relu(dinv*ΣAs + b2) + clip(x)
    k_mfma<true, false, false><<<ggrid, blk, 0, stream>>>(hb, nullptr, Wt2, As,
                                                          dinv, nullptr, nullptr);
    k_aggr<true, true><<<(NN * 64 + 255) / 256, blk, 0, stream>>>(
        (const unsigned int*)As, out, hb, rowptr, esrc, dinv, b2, x);

    // gate: G = [hb | clip(x)] @ Wgt (K=256) ; out = h * sigmoid(G + bg) in-place
    k_mfma<true, true, true><<<ggrid, blk, 0, stream>>>(hb, x, Wgt, nullptr,
                                                        nullptr, bg, out);
}

// Round 9
// 329.866 us; speedup vs baseline: 1.9025x; 1.1346x over previous
//
#include <hip/hip_runtime.h>
#include <hip/hip_bf16.h>

using short8 = __attribute__((ext_vector_type(8))) short;
using f32x4  = __attribute__((ext_vector_type(4))) float;

static constexpr int NN = 50000;   // nodes
static constexpr int NE = 800000;  // edges
static constexpr int NBLK = (NN + 255) / 256;  // 196 scan blocks
static constexpr int MPAD = 50048; // 782 * 64 padded rows for bf16 activations

__device__ __forceinline__ float clip100(float v) { return fminf(fmaxf(v, -100.f), 100.f); }
__device__ __forceinline__ unsigned short f2b(float v) {
    __hip_bfloat16 h = __float2bfloat16(v);
    return *reinterpret_cast<unsigned short*>(&h);
}
__device__ __forceinline__ float blo(unsigned int u) { return __uint_as_float(u << 16); }
__device__ __forceinline__ float bhi(unsigned int u) { return __uint_as_float(u & 0xFFFF0000u); }

// ---------------- CSR build ----------------
__global__ __launch_bounds__(256) void k_hist(const int* __restrict__ idx,
                                              int* __restrict__ cnt) {
    int e = blockIdx.x * 256 + threadIdx.x;
    if (e < NE) atomicAdd(&cnt[idx[NE + e]], 1);
}

__global__ __launch_bounds__(256) void k_bsum(const int* __restrict__ cnt,
                                              int* __restrict__ bsum) {
    __shared__ int ls[256];
    const int t = threadIdx.x;
    const int i = blockIdx.x * 256 + t;
    ls[t] = (i < NN) ? cnt[i] : 0;
    __syncthreads();
    for (int off = 128; off > 0; off >>= 1) {
        if (t < off) ls[t] += ls[t + off];
        __syncthreads();
    }
    if (t == 0) bsum[blockIdx.x] = ls[0];
}

__global__ __launch_bounds__(256) void k_scanb(const int* __restrict__ bsum,
                                               int* __restrict__ bbase,
                                               int* __restrict__ rowptr) {
    __shared__ int ls[256];
    const int t = threadIdx.x;
    ls[t] = (t < NBLK) ? bsum[t] : 0;
    __syncthreads();
    for (int off = 1; off < 256; off <<= 1) {
        const int add = (t >= off) ? ls[t - off] : 0;
        __syncthreads();
        ls[t] += add;
        __syncthreads();
    }
    if (t < NBLK) bbase[t] = (t == 0) ? 0 : ls[t - 1];
    if (t == 0) rowptr[NN] = NE;
}

__global__ __launch_bounds__(256) void k_scan2(int* __restrict__ cnt,
                                               const int* __restrict__ bbase,
                                               int* __restrict__ rowptr,
                                               float* __restrict__ dinv) {
    __shared__ int ls[256];
    const int t = threadIdx.x;
    const int i = blockIdx.x * 256 + t;
    const int c = (i < NN) ? cnt[i] : 0;
    ls[t] = c;
    __syncthreads();
    for (int off = 1; off < 256; off <<= 1) {
        const int add = (t >= off) ? ls[t - off] : 0;
        __syncthreads();
        ls[t] += add;
        __syncthreads();
    }
    if (i < NN) {
        const int excl = bbase[blockIdx.x] + ls[t] - c;
        rowptr[i] = excl;
        cnt[i] = excl;  // fill cursor
        dinv[i] = rsqrtf(1.f + (float)c);
    }
}

__global__ __launch_bounds__(256) void k_fill(const int* __restrict__ idx,
                                              int* __restrict__ cur,
                                              int* __restrict__ esrc) {
    int e = blockIdx.x * 256 + threadIdx.x;
    if (e >= NE) return;
    const int s = idx[e];
    const int d = idx[NE + e];
    const int pos = atomicAdd(&cur[d], 1);
    esrc[pos] = s;
}

// ---------------- weight transpose + bf16 convert (+ cnt zero) ----------------
__global__ __launch_bounds__(256) void k_cvtw(const float* __restrict__ W1,
                                              const float* __restrict__ W2,
                                              const float* __restrict__ Wg,
                                              unsigned short* __restrict__ Wt1,
                                              unsigned short* __restrict__ Wt2,
                                              unsigned short* __restrict__ Wgt,
                                              int* __restrict__ cnt) {
    const int i = blockIdx.x * 256 + threadIdx.x;  // 0..65535
    if (i < NN) cnt[i] = 0;
    if (i < 16384) {
        const int n = i >> 7, k = i & 127;
        Wt1[i] = f2b(W1[k * 128 + n]);
    } else if (i < 32768) {
        const int j = i - 16384;
        const int n = j >> 7, k = j & 127;
        Wt2[j] = f2b(W2[k * 128 + n]);
    } else {
        const int j = i - 32768;
        const int n = j >> 8, k = j & 255;
        Wgt[j] = f2b(Wg[k * 128 + n]);
    }
}

// ---------------- MFMA GEMM (K=128, LDS-staged Wt) ----------------
// C[m][n] = A[m][:] @ W[:][n]; Wt bf16 [128][128] n-major, staged in LDS
// (row pad +8 shorts: 272 B stride keeps ds_read_b128 aligned, <=2-way banks).
// Staging: 2048 short8s total, flat loop 8 x 256 threads (full coverage).
// AB16: A = bf16 activations (rows padded); else A = fp32 Af with clip+guard.
// Epilogue: Cb[row][col] = bf16(acc * dinv[row])  (scaled message buffer).
template <bool AB16>
__global__ __launch_bounds__(256) void k_mfma_lds(const unsigned short* __restrict__ Ab,
                                                  const float* __restrict__ Af,
                                                  const unsigned short* __restrict__ Wt,
                                                  unsigned short* __restrict__ Cb,
                                                  const float* __restrict__ dinv) {
    __shared__ unsigned short wl[128 * 136];
    const int tid = threadIdx.x;
#pragma unroll
    for (int j = tid; j < 2048; j += 256) {       // 2048 = 128 rows x 16 short8
        const int row = j >> 4, c8 = j & 15;
        *(short8*)(wl + row * 136 + c8 * 8) = *(const short8*)(Wt + row * 128 + c8 * 8);
    }
    __syncthreads();

    const int wv = tid >> 6;
    const int ln = tid & 63;
    const int l16 = ln & 15;
    const int qd = ln >> 4;
    const int rowb = blockIdx.x * 64 + wv * 16;
    const long arow = rowb + l16;
    const int kq = qd * 8;

    f32x4 acc[8];
#pragma unroll
    for (int i = 0; i < 8; ++i) acc[i] = (f32x4){0.f, 0.f, 0.f, 0.f};

#pragma unroll
    for (int kc = 0; kc < 4; ++kc) {
        short8 a;
        if (AB16) {
            a = *(const short8*)(Ab + arow * 128 + kc * 32 + kq);
        } else {
            a = (short8){0, 0, 0, 0, 0, 0, 0, 0};
            if (arow < NN) {
                const float* fp = Af + arow * 128 + kc * 32 + kq;
                const float4 f0 = *(const float4*)fp;
                const float4 f1 = *(const float4*)(fp + 4);
                a[0] = (short)f2b(clip100(f0.x));
                a[1] = (short)f2b(clip100(f0.y));
                a[2] = (short)f2b(clip100(f0.z));
                a[3] = (short)f2b(clip100(f0.w));
                a[4] = (short)f2b(clip100(f1.x));
                a[5] = (short)f2b(clip100(f1.y));
                a[6] = (short)f2b(clip100(f1.z));
                a[7] = (short)f2b(clip100(f1.w));
            }
        }
#pragma unroll
        for (int nt = 0; nt < 8; ++nt) {
            const short8 b = *(const short8*)(wl + (nt * 16 + l16) * 136 + kc * 32 + kq);
            acc[nt] = __builtin_amdgcn_mfma_f32_16x16x32_bf16(a, b, acc[nt], 0, 0, 0);
        }
    }

    const int r0 = rowb + qd * 4;
#pragma unroll
    for (int r = 0; r < 4; ++r) {
        const int row = r0 + r;
        if (row < NN) {
            const float dv = dinv[row];
#pragma unroll
            for (int nt = 0; nt < 8; ++nt) {
                Cb[(long)row * 128 + nt * 16 + l16] = f2b(acc[nt][r] * dv);
            }
        }
    }
}

// ---------------- gate MFMA (K=256, direct-global B) ----------------
// G = [hb | clip(x)] @ Wgt ; H[row][col] *= sigmoid(G + bg[col]) in place.
__global__ __launch_bounds__(256) void k_mfma_gate(const unsigned short* __restrict__ Ab,
                                                   const float* __restrict__ Af,
                                                   const unsigned short* __restrict__ Wt,
                                                   const float* __restrict__ bg,
                                                   float* __restrict__ H) {
    constexpr int K = 256;
    const int wv = threadIdx.x >> 6;
    const int ln = threadIdx.x & 63;
    const int l16 = ln & 15;
    const int qd = ln >> 4;
    const int rowb = blockIdx.x * 64 + wv * 16;
    const long arow = rowb + l16;
    const int kq = qd * 8;

    f32x4 acc[8];
#pragma unroll
    for (int i = 0; i < 8; ++i) acc[i] = (f32x4){0.f, 0.f, 0.f, 0.f};

    {
        const unsigned short* ap = Ab + arow * 128 + kq;
#pragma unroll
        for (int kc = 0; kc < 4; ++kc) {
            const short8 a = *(const short8*)(ap + kc * 32);
#pragma unroll
            for (int nt = 0; nt < 8; ++nt) {
                const short8 b = *(const short8*)(Wt + (long)(nt * 16 + l16) * K + kc * 32 + kq);
                acc[nt] = __builtin_amdgcn_mfma_f32_16x16x32_bf16(a, b, acc[nt], 0, 0, 0);
            }
        }
    }
    {
        const bool valid = arow < NN;
        const float* fp = Af + arow * 128 + kq;
#pragma unroll
        for (int kc = 0; kc < 4; ++kc) {
            short8 a = (short8){0, 0, 0, 0, 0, 0, 0, 0};
            if (valid) {
                const float4 f0 = *(const float4*)(fp + kc * 32);
                const float4 f1 = *(const float4*)(fp + kc * 32 + 4);
                a[0] = (short)f2b(clip100(f0.x));
                a[1] = (short)f2b(clip100(f0.y));
                a[2] = (short)f2b(clip100(f0.z));
                a[3] = (short)f2b(clip100(f0.w));
                a[4] = (short)f2b(clip100(f1.x));
                a[5] = (short)f2b(clip100(f1.y));
                a[6] = (short)f2b(clip100(f1.z));
                a[7] = (short)f2b(clip100(f1.w));
            }
#pragma unroll
            for (int nt = 0; nt < 8; ++nt) {
                const short8 b = *(const short8*)(Wt + (long)(nt * 16 + l16) * K + 128 + kc * 32 + kq);
                acc[nt] = __builtin_amdgcn_mfma_f32_16x16x32_bf16(a, b, acc[nt], 0, 0, 0);
            }
        }
    }

    const int r0 = rowb + qd * 4;
#pragma unroll
    for (int nt = 0; nt < 8; ++nt) {
        const int col = nt * 16 + l16;
        const float bgv = bg[col];
#pragma unroll
        for (int r = 0; r < 4; ++r) {
            const int row = r0 + r;
            if (row < NN) {
                const float g = 1.f / (1.f + __expf(-(acc[nt][r] + bgv)));
                H[(long)row * 128 + col] *= g;
            }
        }
    }
}

// ---------------- fused aggregation (bf16 scaled messages, 4x MLP unroll) ----
// One wave per node d; lane owns cols [2*lane, 2*lane+1] packed in one uint.
// acc = dinv[d] * ( sum_{e: dst=d} As[src] + As[d] ); B = relu(acc + bias)
// (+ clip(x[d]) if RES). fp32 accumulate.
template <bool RES, bool WF32>
__global__ __launch_bounds__(256) void k_aggr(const unsigned int* __restrict__ As2,
                                              float* __restrict__ Bf,
                                              unsigned short* __restrict__ Bb,
                                              const int* __restrict__ rowptr,
                                              const int* __restrict__ esrc,
                                              const float* __restrict__ dinv,
                                              const float* __restrict__ bias,
                                              const float* __restrict__ x) {
    const int d = (blockIdx.x * 256 + threadIdx.x) >> 6;
    if (d >= NN) return;
    const int lane = threadIdx.x & 63;
    const float dd = dinv[d];

    const unsigned int u = As2[(long)d * 64 + lane];  // self term
    float2 acc;
    acc.x = blo(u);
    acc.y = bhi(u);

    const int beg = rowptr[d];
    const int end = rowptr[d + 1];
    int i = beg;
    for (; i + 4 <= end; i += 4) {
        const int s0 = esrc[i + 0];
        const int s1 = esrc[i + 1];
        const int s2 = esrc[i + 2];
        const int s3 = esrc[i + 3];
        const unsigned int v0 = As2[(long)s0 * 64 + lane];
        const unsigned int v1 = As2[(long)s1 * 64 + lane];
        const unsigned int v2 = As2[(long)s2 * 64 + lane];
        const unsigned int v3 = As2[(long)s3 * 64 + lane];
        acc.x += (blo(v0) + blo(v1)) + (blo(v2) + blo(v3));
        acc.y += (bhi(v0) + bhi(v1)) + (bhi(v2) + bhi(v3));
    }
    for (; i < end; ++i) {
        const unsigned int v = As2[(long)esrc[i] * 64 + lane];
        acc.x += blo(v);
        acc.y += bhi(v);
    }

    const float2 bv = ((const float2*)bias)[lane];
    acc.x = fmaxf(fmaf(acc.x, dd, bv.x), 0.f);
    acc.y = fmaxf(fmaf(acc.y, dd, bv.y), 0.f);
    if (RES) {
        const float2 xv = ((const float2*)x)[(long)d * 64 + lane];
        acc.x += clip100(xv.x);
        acc.y += clip100(xv.y);
    }
    if (WF32) ((float2*)Bf)[(long)d * 64 + lane] = acc;
    const unsigned int pack = (unsigned int)f2b(acc.x) | ((unsigned int)f2b(acc.y) << 16);
    ((unsigned int*)Bb)[(long)d * 64 + lane] = pack;
}

// ---------------- launch ----------------
extern "C" void kernel_launch(void* const* d_in, const int* in_sizes, int n_in,
                              void* d_out, int out_size, void* d_ws, size_t ws_size,
                              hipStream_t stream) {
    const float* x  = (const float*)d_in[0];
    const int*  eix = (const int*)d_in[1];
    const float* W1 = (const float*)d_in[2];
    const float* b1 = (const float*)d_in[3];
    const float* W2 = (const float*)d_in[4];
    const float* b2 = (const float*)d_in[5];
    const float* Wg = (const float*)d_in[6];
    const float* bg = (const float*)d_in[7];
    float* out = (float*)d_out;

    char* ws = (char*)d_ws;
    unsigned short* As   = (unsigned short*)ws;                     // 12,812,288 B
    unsigned short* hb   = (unsigned short*)(ws + 12812288);        // 12,812,288 B
    unsigned short* Wt1  = (unsigned short*)(ws + 25624576);        // 32,768 B
    unsigned short* Wt2  = (unsigned short*)(ws + 25657344);        // 32,768 B
    unsigned short* Wgt  = (unsigned short*)(ws + 25690112);        // 65,536 B
    int*   cnt    = (int*)(ws + 25755648);                          // 200,704 B
    int*   rowptr = (int*)(ws + 25956352);                          // 200,704 B
    float* dinv   = (float*)(ws + 26157056);                        // 200,704 B
    int*   bsum   = (int*)(ws + 26357760);                          // 4,096 B
    int*   bbase  = (int*)(ws + 26361856);                          // 4,096 B
    int*   esrc   = (int*)(ws + 26365952);                          // 3,200,000 B

    const int ggrid = MPAD / 64;  // 782
    dim3 blk(256);

    // weight conversion (also zeroes cnt), then CSR + normalization
    k_cvtw<<<256, blk, 0, stream>>>(W1, W2, Wg, Wt1, Wt2, Wgt, cnt);
    k_hist<<<(NE + 255) / 256, blk, 0, stream>>>(eix, cnt);
    k_bsum<<<NBLK, blk, 0, stream>>>(cnt, bsum);
    k_scanb<<<1, blk, 0, stream>>>(bsum, bbase, rowptr);
    k_scan2<<<NBLK, blk, 0, stream>>>(cnt, bbase, rowptr, dinv);
    k_fill<<<(NE + 255) / 256, blk, 0, stream>>>(eix, cnt, esrc);

    // layer 1: As = bf16((clip(x)@W1) * dinv) ; h1b = bf16(relu(dinv*ΣAs + b1))
    k_mfma_lds<false><<<ggrid, blk, 0, stream>>>(nullptr, x, Wt1, As, dinv);
    k_aggr<false, false><<<(NN * 64 + 255) / 256, blk, 0, stream>>>(
        (const unsigned int*)As, nullptr, hb, rowptr, esrc, dinv, b1, nullptr);

    // layer 2: As = bf16((h1b@W2) * dinv) ; h = relu(dinv*ΣAs + b2) + clip(x)
    k_mfma_lds<true><<<ggrid, blk, 0, stream>>>(hb, nullptr, Wt2, As, dinv);
    k_aggr<true, true><<<(NN * 64 + 255) / 256, blk, 0, stream>>>(
        (const unsigned int*)As, out, hb, rowptr, esrc, dinv, b2, x);

    // gate: G = [hb | clip(x)] @ Wgt (K=256) ; out = h * sigmoid(G + bg) in-place
    k_mfma_gate<<<ggrid, blk, 0, stream>>>(hb, x, Wgt, bg, out);
}

// Round 10
// 318.828 us; speedup vs baseline: 1.9684x; 1.0346x over previous
//
#include <hip/hip_runtime.h>
#include <hip/hip_bf16.h>

using short8 = __attribute__((ext_vector_type(8))) short;
using f32x4  = __attribute__((ext_vector_type(4))) float;

static constexpr int NN = 50000;   // nodes
static constexpr int NE = 800000;  // edges
static constexpr int NBLK = (NN + 255) / 256;  // 196 scan blocks
static constexpr int MPAD = 50048; // 782 * 64 padded rows for bf16 activations
static constexpr int NPART = 8;    // XCD partitions (dst ranges)
static constexpr int PCH = NN / NPART;          // 6250 nodes per partition
static constexpr int NCHUNK = 98;               // edge chunks
static constexpr int CHUNK = (NE + NCHUNK - 1) / NCHUNK;  // 8164

__device__ __forceinline__ float clip100(float v) { return fminf(fmaxf(v, -100.f), 100.f); }
__device__ __forceinline__ unsigned short f2b(float v) {
    __hip_bfloat16 h = __float2bfloat16(v);
    return *reinterpret_cast<unsigned short*>(&h);
}
__device__ __forceinline__ float blo(unsigned int u) { return __uint_as_float(u << 16); }
__device__ __forceinline__ float bhi(unsigned int u) { return __uint_as_float(u & 0xFFFF0000u); }

// ---------------- CSR build (XCD-partitioned: p = blockIdx&7 ~ XCD id) -------
// Each block scans one edge chunk, handles only dst in its partition ->
// cnt/esrc lines are written by one XCD only (kills cross-XCD false sharing).
__global__ __launch_bounds__(256) void k_hist(const int* __restrict__ idx,
                                              int* __restrict__ cnt) {
    const int p = blockIdx.x & 7;
    const int c = blockIdx.x >> 3;
    const int beg = c * CHUNK;
    const int end = min(NE, beg + CHUNK);
    for (int e = beg + threadIdx.x; e < end; e += 256) {
        const int d = idx[NE + e];
        if (d / PCH == p) atomicAdd(&cnt[d], 1);
    }
}

__global__ __launch_bounds__(256) void k_fill(const int* __restrict__ idx,
                                              int* __restrict__ cur,
                                              int* __restrict__ esrc) {
    const int p = blockIdx.x & 7;
    const int c = blockIdx.x >> 3;
    const int beg = c * CHUNK;
    const int end = min(NE, beg + CHUNK);
    for (int e = beg + threadIdx.x; e < end; e += 256) {
        const int d = idx[NE + e];
        if (d / PCH == p) {
            const int s = idx[e];
            const int pos = atomicAdd(&cur[d], 1);
            esrc[pos] = s;
        }
    }
}

__global__ __launch_bounds__(256) void k_bsum(const int* __restrict__ cnt,
                                              int* __restrict__ bsum) {
    __shared__ int ls[256];
    const int t = threadIdx.x;
    const int i = blockIdx.x * 256 + t;
    ls[t] = (i < NN) ? cnt[i] : 0;
    __syncthreads();
    for (int off = 128; off > 0; off >>= 1) {
        if (t < off) ls[t] += ls[t + off];
        __syncthreads();
    }
    if (t == 0) bsum[blockIdx.x] = ls[0];
}

__global__ __launch_bounds__(256) void k_scanb(const int* __restrict__ bsum,
                                               int* __restrict__ bbase,
                                               int* __restrict__ rowptr) {
    __shared__ int ls[256];
    const int t = threadIdx.x;
    ls[t] = (t < NBLK) ? bsum[t] : 0;
    __syncthreads();
    for (int off = 1; off < 256; off <<= 1) {
        const int add = (t >= off) ? ls[t - off] : 0;
        __syncthreads();
        ls[t] += add;
        __syncthreads();
    }
    if (t < NBLK) bbase[t] = (t == 0) ? 0 : ls[t - 1];
    if (t == 0) rowptr[NN] = NE;
}

__global__ __launch_bounds__(256) void k_scan2(int* __restrict__ cnt,
                                               const int* __restrict__ bbase,
                                               int* __restrict__ rowptr,
                                               float* __restrict__ dinv) {
    __shared__ int ls[256];
    const int t = threadIdx.x;
    const int i = blockIdx.x * 256 + t;
    const int c = (i < NN) ? cnt[i] : 0;
    ls[t] = c;
    __syncthreads();
    for (int off = 1; off < 256; off <<= 1) {
        const int add = (t >= off) ? ls[t - off] : 0;
        __syncthreads();
        ls[t] += add;
        __syncthreads();
    }
    if (i < NN) {
        const int excl = bbase[blockIdx.x] + ls[t] - c;
        rowptr[i] = excl;
        cnt[i] = excl;  // fill cursor
        dinv[i] = rsqrtf(1.f + (float)c);
    }
}

// ---------------- weight transpose + bf16 convert (+ cnt zero) ----------------
__global__ __launch_bounds__(256) void k_cvtw(const float* __restrict__ W1,
                                              const float* __restrict__ W2,
                                              const float* __restrict__ Wg,
                                              unsigned short* __restrict__ Wt1,
                                              unsigned short* __restrict__ Wt2,
                                              unsigned short* __restrict__ Wgt,
                                              int* __restrict__ cnt) {
    const int i = blockIdx.x * 256 + threadIdx.x;  // 0..65535
    if (i < NN) cnt[i] = 0;
    if (i < 16384) {
        const int n = i >> 7, k = i & 127;
        Wt1[i] = f2b(W1[k * 128 + n]);
    } else if (i < 32768) {
        const int j = i - 16384;
        const int n = j >> 7, k = j & 127;
        Wt2[j] = f2b(W2[k * 128 + n]);
    } else {
        const int j = i - 32768;
        const int n = j >> 8, k = j & 255;
        Wgt[j] = f2b(Wg[k * 128 + n]);
    }
}

// ---------------- MFMA GEMM (K=128, LDS-staged Wt) ----------------
template <bool AB16>
__global__ __launch_bounds__(256) void k_mfma_lds(const unsigned short* __restrict__ Ab,
                                                  const float* __restrict__ Af,
                                                  const unsigned short* __restrict__ Wt,
                                                  unsigned short* __restrict__ Cb,
                                                  const float* __restrict__ dinv) {
    __shared__ unsigned short wl[128 * 136];
    const int tid = threadIdx.x;
#pragma unroll
    for (int j = tid; j < 2048; j += 256) {       // 2048 = 128 rows x 16 short8
        const int row = j >> 4, c8 = j & 15;
        *(short8*)(wl + row * 136 + c8 * 8) = *(const short8*)(Wt + row * 128 + c8 * 8);
    }
    __syncthreads();

    const int wv = tid >> 6;
    const int ln = tid & 63;
    const int l16 = ln & 15;
    const int qd = ln >> 4;
    const int rowb = blockIdx.x * 64 + wv * 16;
    const long arow = rowb + l16;
    const int kq = qd * 8;

    f32x4 acc[8];
#pragma unroll
    for (int i = 0; i < 8; ++i) acc[i] = (f32x4){0.f, 0.f, 0.f, 0.f};

#pragma unroll
    for (int kc = 0; kc < 4; ++kc) {
        short8 a;
        if (AB16) {
            a = *(const short8*)(Ab + arow * 128 + kc * 32 + kq);
        } else {
            a = (short8){0, 0, 0, 0, 0, 0, 0, 0};
            if (arow < NN) {
                const float* fp = Af + arow * 128 + kc * 32 + kq;
                const float4 f0 = *(const float4*)fp;
                const float4 f1 = *(const float4*)(fp + 4);
                a[0] = (short)f2b(clip100(f0.x));
                a[1] = (short)f2b(clip100(f0.y));
                a[2] = (short)f2b(clip100(f0.z));
                a[3] = (short)f2b(clip100(f0.w));
                a[4] = (short)f2b(clip100(f1.x));
                a[5] = (short)f2b(clip100(f1.y));
                a[6] = (short)f2b(clip100(f1.z));
                a[7] = (short)f2b(clip100(f1.w));
            }
        }
#pragma unroll
        for (int nt = 0; nt < 8; ++nt) {
            const short8 b = *(const short8*)(wl + (nt * 16 + l16) * 136 + kc * 32 + kq);
            acc[nt] = __builtin_amdgcn_mfma_f32_16x16x32_bf16(a, b, acc[nt], 0, 0, 0);
        }
    }

    const int r0 = rowb + qd * 4;
#pragma unroll
    for (int r = 0; r < 4; ++r) {
        const int row = r0 + r;
        if (row < NN) {
            const float dv = dinv[row];
#pragma unroll
            for (int nt = 0; nt < 8; ++nt) {
                Cb[(long)row * 128 + nt * 16 + l16] = f2b(acc[nt][r] * dv);
            }
        }
    }
}

// ---------------- gate MFMA (K=256, direct-global B) ----------------
__global__ __launch_bounds__(256) void k_mfma_gate(const unsigned short* __restrict__ Ab,
                                                   const float* __restrict__ Af,
                                                   const unsigned short* __restrict__ Wt,
                                                   const float* __restrict__ bg,
                                                   float* __restrict__ H) {
    constexpr int K = 256;
    const int wv = threadIdx.x >> 6;
    const int ln = threadIdx.x & 63;
    const int l16 = ln & 15;
    const int qd = ln >> 4;
    const int rowb = blockIdx.x * 64 + wv * 16;
    const long arow = rowb + l16;
    const int kq = qd * 8;

    f32x4 acc[8];
#pragma unroll
    for (int i = 0; i < 8; ++i) acc[i] = (f32x4){0.f, 0.f, 0.f, 0.f};

    {
        const unsigned short* ap = Ab + arow * 128 + kq;
#pragma unroll
        for (int kc = 0; kc < 4; ++kc) {
            const short8 a = *(const short8*)(ap + kc * 32);
#pragma unroll
            for (int nt = 0; nt < 8; ++nt) {
                const short8 b = *(const short8*)(Wt + (long)(nt * 16 + l16) * K + kc * 32 + kq);
                acc[nt] = __builtin_amdgcn_mfma_f32_16x16x32_bf16(a, b, acc[nt], 0, 0, 0);
            }
        }
    }
    {
        const bool valid = arow < NN;
        const float* fp = Af + arow * 128 + kq;
#pragma unroll
        for (int kc = 0; kc < 4; ++kc) {
            short8 a = (short8){0, 0, 0, 0, 0, 0, 0, 0};
            if (valid) {
                const float4 f0 = *(const float4*)(fp + kc * 32);
                const float4 f1 = *(const float4*)(fp + kc * 32 + 4);
                a[0] = (short)f2b(clip100(f0.x));
                a[1] = (short)f2b(clip100(f0.y));
                a[2] = (short)f2b(clip100(f0.z));
                a[3] = (short)f2b(clip100(f0.w));
                a[4] = (short)f2b(clip100(f1.x));
                a[5] = (short)f2b(clip100(f1.y));
                a[6] = (short)f2b(clip100(f1.z));
                a[7] = (short)f2b(clip100(f1.w));
            }
#pragma unroll
            for (int nt = 0; nt < 8; ++nt) {
                const short8 b = *(const short8*)(Wt + (long)(nt * 16 + l16) * K + 128 + kc * 32 + kq);
                acc[nt] = __builtin_amdgcn_mfma_f32_16x16x32_bf16(a, b, acc[nt], 0, 0, 0);
            }
        }
    }

    const int r0 = rowb + qd * 4;
#pragma unroll
    for (int nt = 0; nt < 8; ++nt) {
        const int col = nt * 16 + l16;
        const float bgv = bg[col];
#pragma unroll
        for (int r = 0; r < 4; ++r) {
            const int row = r0 + r;
            if (row < NN) {
                const float g = 1.f / (1.f + __expf(-(acc[nt][r] + bgv)));
                H[(long)row * 128 + col] *= g;
            }
        }
    }
}

// ---------------- fused aggregation (bf16 scaled messages, 4x MLP unroll) ----
template <bool RES, bool WF32>
__global__ __launch_bounds__(256) void k_aggr(const unsigned int* __restrict__ As2,
                                              float* __restrict__ Bf,
                                              unsigned short* __restrict__ Bb,
                                              const int* __restrict__ rowptr,
                                              const int* __restrict__ esrc,
                                              const float* __restrict__ dinv,
                                              const float* __restrict__ bias,
                                              const float* __restrict__ x) {
    const int d = (blockIdx.x * 256 + threadIdx.x) >> 6;
    if (d >= NN) return;
    const int lane = threadIdx.x & 63;
    const float dd = dinv[d];

    const unsigned int u = As2[(long)d * 64 + lane];  // self term
    float2 acc;
    acc.x = blo(u);
    acc.y = bhi(u);

    const int beg = rowptr[d];
    const int end = rowptr[d + 1];
    int i = beg;
    for (; i + 4 <= end; i += 4) {
        const int s0 = esrc[i + 0];
        const int s1 = esrc[i + 1];
        const int s2 = esrc[i + 2];
        const int s3 = esrc[i + 3];
        const unsigned int v0 = As2[(long)s0 * 64 + lane];
        const unsigned int v1 = As2[(long)s1 * 64 + lane];
        const unsigned int v2 = As2[(long)s2 * 64 + lane];
        const unsigned int v3 = As2[(long)s3 * 64 + lane];
        acc.x += (blo(v0) + blo(v1)) + (blo(v2) + blo(v3));
        acc.y += (bhi(v0) + bhi(v1)) + (bhi(v2) + bhi(v3));
    }
    for (; i < end; ++i) {
        const unsigned int v = As2[(long)esrc[i] * 64 + lane];
        acc.x += blo(v);
        acc.y += bhi(v);
    }

    const float2 bv = ((const float2*)bias)[lane];
    acc.x = fmaxf(fmaf(acc.x, dd, bv.x), 0.f);
    acc.y = fmaxf(fmaf(acc.y, dd, bv.y), 0.f);
    if (RES) {
        const float2 xv = ((const float2*)x)[(long)d * 64 + lane];
        acc.x += clip100(xv.x);
        acc.y += clip100(xv.y);
    }
    if (WF32) ((float2*)Bf)[(long)d * 64 + lane] = acc;
    const unsigned int pack = (unsigned int)f2b(acc.x) | ((unsigned int)f2b(acc.y) << 16);
    ((unsigned int*)Bb)[(long)d * 64 + lane] = pack;
}

// ---------------- launch ----------------
extern "C" void kernel_launch(void* const* d_in, const int* in_sizes, int n_in,
                              void* d_out, int out_size, void* d_ws, size_t ws_size,
                              hipStream_t stream) {
    const float* x  = (const float*)d_in[0];
    const int*  eix = (const int*)d_in[1];
    const float* W1 = (const float*)d_in[2];
    const float* b1 = (const float*)d_in[3];
    const float* W2 = (const float*)d_in[4];
    const float* b2 = (const float*)d_in[5];
    const float* Wg = (const float*)d_in[6];
    const float* bg = (const float*)d_in[7];
    float* out = (float*)d_out;

    char* ws = (char*)d_ws;
    unsigned short* As   = (unsigned short*)ws;                     // 12,812,288 B
    unsigned short* hb   = (unsigned short*)(ws + 12812288);        // 12,812,288 B
    unsigned short* Wt1  = (unsigned short*)(ws + 25624576);        // 32,768 B
    unsigned short* Wt2  = (unsigned short*)(ws + 25657344);        // 32,768 B
    unsigned short* Wgt  = (unsigned short*)(ws + 25690112);        // 65,536 B
    int*   cnt    = (int*)(ws + 25755648);                          // 200,704 B
    int*   rowptr = (int*)(ws + 25956352);                          // 200,704 B
    float* dinv   = (float*)(ws + 26157056);                        // 200,704 B
    int*   bsum   = (int*)(ws + 26357760);                          // 4,096 B
    int*   bbase  = (int*)(ws + 26361856);                          // 4,096 B
    int*   esrc   = (int*)(ws + 26365952);                          // 3,200,000 B

    const int ggrid = MPAD / 64;  // 782
    dim3 blk(256);

    // weight conversion (also zeroes cnt), then CSR + normalization
    k_cvtw<<<256, blk, 0, stream>>>(W1, W2, Wg, Wt1, Wt2, Wgt, cnt);
    k_hist<<<NPART * NCHUNK, blk, 0, stream>>>(eix, cnt);
    k_bsum<<<NBLK, blk, 0, stream>>>(cnt, bsum);
    k_scanb<<<1, blk, 0, stream>>>(bsum, bbase, rowptr);
    k_scan2<<<NBLK, blk, 0, stream>>>(cnt, bbase, rowptr, dinv);
    k_fill<<<NPART * NCHUNK, blk, 0, stream>>>(eix, cnt, esrc);

    // layer 1: As = bf16((clip(x)@W1) * dinv) ; h1b = bf16(relu(dinv*ΣAs + b1))
    k_mfma_lds<false><<<ggrid, blk, 0, stream>>>(nullptr, x, Wt1, As, dinv);
    k_aggr<false, false><<<(NN * 64 + 255) / 256, blk, 0, stream>>>(
        (const unsigned int*)As, nullptr, hb, rowptr, esrc, dinv, b1, nullptr);

    // layer 2: As = bf16((h1b@W2) * dinv) ; h = relu(dinv*ΣAs + b2) + clip(x)
    k_mfma_lds<true><<<ggrid, blk, 0, stream>>>(hb, nullptr, Wt2, As, dinv);
    k_aggr<true, true><<<(NN * 64 + 255) / 256, blk, 0, stream>>>(
        (const unsigned int*)As, out, hb, rowptr, esrc, dinv, b2, x);

    // gate: G = [hb | clip(x)] @ Wgt (K=256) ; out = h * sigmoid(G + bg) in-place
    k_mfma_gate<<<ggrid, blk, 0, stream>>>(hb, x, Wgt, bg, out);
}

// Round 11
// 302.451 us; speedup vs baseline: 2.0750x; 1.0541x over previous
//
#include <hip/hip_runtime.h>
#include <hip/hip_bf16.h>

using short8 = __attribute__((ext_vector_type(8))) short;
using f32x4  = __attribute__((ext_vector_type(4))) float;

static constexpr int NN = 50000;   // nodes
static constexpr int NE = 800000;  // edges
static constexpr int NBLK = (NN + 255) / 256;  // 196 scan blocks
static constexpr int MPAD = 50048; // 782 * 64 padded rows for bf16 activations
static constexpr int NPART = 8;    // XCD partitions (dst ranges)
static constexpr int PCH = NN / NPART;          // 6250 nodes per partition
static constexpr int NCHUNK = 98;               // edge chunks
static constexpr int CHUNK = (NE + NCHUNK - 1) / NCHUNK;  // 8164

__device__ __forceinline__ float clip100(float v) { return fminf(fmaxf(v, -100.f), 100.f); }
__device__ __forceinline__ unsigned short f2b(float v) {
    __hip_bfloat16 h = __float2bfloat16(v);
    return *reinterpret_cast<unsigned short*>(&h);
}
__device__ __forceinline__ float blo(unsigned int u) { return __uint_as_float(u << 16); }
__device__ __forceinline__ float bhi(unsigned int u) { return __uint_as_float(u & 0xFFFF0000u); }
__device__ __forceinline__ float b2f(unsigned short u) {
    return __uint_as_float(((unsigned int)u) << 16);
}

// ---------------- CSR build (XCD-partitioned: p = blockIdx&7 ~ XCD id) -------
__global__ __launch_bounds__(256) void k_hist(const int* __restrict__ idx,
                                              int* __restrict__ cnt) {
    const int p = blockIdx.x & 7;
    const int c = blockIdx.x >> 3;
    const int beg = c * CHUNK;
    const int end = min(NE, beg + CHUNK);
    for (int e = beg + threadIdx.x; e < end; e += 256) {
        const int d = idx[NE + e];
        if (d / PCH == p) atomicAdd(&cnt[d], 1);
    }
}

__global__ __launch_bounds__(256) void k_fill(const int* __restrict__ idx,
                                              int* __restrict__ cur,
                                              int* __restrict__ esrc) {
    const int p = blockIdx.x & 7;
    const int c = blockIdx.x >> 3;
    const int beg = c * CHUNK;
    const int end = min(NE, beg + CHUNK);
    for (int e = beg + threadIdx.x; e < end; e += 256) {
        const int d = idx[NE + e];
        if (d / PCH == p) {
            const int s = idx[e];
            const int pos = atomicAdd(&cur[d], 1);
            esrc[pos] = s;
        }
    }
}

__global__ __launch_bounds__(256) void k_bsum(const int* __restrict__ cnt,
                                              int* __restrict__ bsum) {
    __shared__ int ls[256];
    const int t = threadIdx.x;
    const int i = blockIdx.x * 256 + t;
    ls[t] = (i < NN) ? cnt[i] : 0;
    __syncthreads();
    for (int off = 128; off > 0; off >>= 1) {
        if (t < off) ls[t] += ls[t + off];
        __syncthreads();
    }
    if (t == 0) bsum[blockIdx.x] = ls[0];
}

__global__ __launch_bounds__(256) void k_scanb(const int* __restrict__ bsum,
                                               int* __restrict__ bbase,
                                               int* __restrict__ rowptr) {
    __shared__ int ls[256];
    const int t = threadIdx.x;
    ls[t] = (t < NBLK) ? bsum[t] : 0;
    __syncthreads();
    for (int off = 1; off < 256; off <<= 1) {
        const int add = (t >= off) ? ls[t - off] : 0;
        __syncthreads();
        ls[t] += add;
        __syncthreads();
    }
    if (t < NBLK) bbase[t] = (t == 0) ? 0 : ls[t - 1];
    if (t == 0) rowptr[NN] = NE;
}

__global__ __launch_bounds__(256) void k_scan2(int* __restrict__ cnt,
                                               const int* __restrict__ bbase,
                                               int* __restrict__ rowptr,
                                               float* __restrict__ dinv) {
    __shared__ int ls[256];
    const int t = threadIdx.x;
    const int i = blockIdx.x * 256 + t;
    const int c = (i < NN) ? cnt[i] : 0;
    ls[t] = c;
    __syncthreads();
    for (int off = 1; off < 256; off <<= 1) {
        const int add = (t >= off) ? ls[t - off] : 0;
        __syncthreads();
        ls[t] += add;
        __syncthreads();
    }
    if (i < NN) {
        const int excl = bbase[blockIdx.x] + ls[t] - c;
        rowptr[i] = excl;
        cnt[i] = excl;  // fill cursor
        dinv[i] = rsqrtf(1.f + (float)c);
    }
}

// ---------------- weight transpose + bf16 convert (+ cnt zero) ----------------
__global__ __launch_bounds__(256) void k_cvtw(const float* __restrict__ W1,
                                              const float* __restrict__ W2,
                                              const float* __restrict__ Wg,
                                              unsigned short* __restrict__ Wt1,
                                              unsigned short* __restrict__ Wt2,
                                              unsigned short* __restrict__ Wgt,
                                              int* __restrict__ cnt) {
    const int i = blockIdx.x * 256 + threadIdx.x;  // 0..65535
    if (i < NN) cnt[i] = 0;
    if (i < 16384) {
        const int n = i >> 7, k = i & 127;
        Wt1[i] = f2b(W1[k * 128 + n]);
    } else if (i < 32768) {
        const int j = i - 16384;
        const int n = j >> 7, k = j & 127;
        Wt2[j] = f2b(W2[k * 128 + n]);
    } else {
        const int j = i - 32768;
        const int n = j >> 8, k = j & 255;
        Wgt[j] = f2b(Wg[k * 128 + n]);
    }
}

// ---------------- MFMA GEMM (K=128, LDS-staged Wt) ----------------
template <bool AB16>
__global__ __launch_bounds__(256) void k_mfma_lds(const unsigned short* __restrict__ Ab,
                                                  const float* __restrict__ Af,
                                                  const unsigned short* __restrict__ Wt,
                                                  unsigned short* __restrict__ Cb,
                                                  const float* __restrict__ dinv) {
    __shared__ unsigned short wl[128 * 136];
    const int tid = threadIdx.x;
#pragma unroll
    for (int j = tid; j < 2048; j += 256) {       // 2048 = 128 rows x 16 short8
        const int row = j >> 4, c8 = j & 15;
        *(short8*)(wl + row * 136 + c8 * 8) = *(const short8*)(Wt + row * 128 + c8 * 8);
    }
    __syncthreads();

    const int wv = tid >> 6;
    const int ln = tid & 63;
    const int l16 = ln & 15;
    const int qd = ln >> 4;
    const int rowb = blockIdx.x * 64 + wv * 16;
    const long arow = rowb + l16;
    const int kq = qd * 8;

    f32x4 acc[8];
#pragma unroll
    for (int i = 0; i < 8; ++i) acc[i] = (f32x4){0.f, 0.f, 0.f, 0.f};

#pragma unroll
    for (int kc = 0; kc < 4; ++kc) {
        short8 a;
        if (AB16) {
            a = *(const short8*)(Ab + arow * 128 + kc * 32 + kq);
        } else {
            a = (short8){0, 0, 0, 0, 0, 0, 0, 0};
            if (arow < NN) {
                const float* fp = Af + arow * 128 + kc * 32 + kq;
                const float4 f0 = *(const float4*)fp;
                const float4 f1 = *(const float4*)(fp + 4);
                a[0] = (short)f2b(clip100(f0.x));
                a[1] = (short)f2b(clip100(f0.y));
                a[2] = (short)f2b(clip100(f0.z));
                a[3] = (short)f2b(clip100(f0.w));
                a[4] = (short)f2b(clip100(f1.x));
                a[5] = (short)f2b(clip100(f1.y));
                a[6] = (short)f2b(clip100(f1.z));
                a[7] = (short)f2b(clip100(f1.w));
            }
        }
#pragma unroll
        for (int nt = 0; nt < 8; ++nt) {
            const short8 b = *(const short8*)(wl + (nt * 16 + l16) * 136 + kc * 32 + kq);
            acc[nt] = __builtin_amdgcn_mfma_f32_16x16x32_bf16(a, b, acc[nt], 0, 0, 0);
        }
    }

    const int r0 = rowb + qd * 4;
#pragma unroll
    for (int r = 0; r < 4; ++r) {
        const int row = r0 + r;
        if (row < NN) {
            const float dv = dinv[row];
#pragma unroll
            for (int nt = 0; nt < 8; ++nt) {
                Cb[(long)row * 128 + nt * 16 + l16] = f2b(acc[nt][r] * dv);
            }
        }
    }
}

// ---------------- gate MFMA (K=256, LDS-staged Wgt, write-only epilogue) -----
// G = [hb | clip(x)] @ Wgt ; out[row][col] = b2f(hb[row][col]) * sigmoid(G+bg).
// Wgt LDS tile: 128 rows x 264 shorts (pad +8) = 67.6 KB -> 2 blocks/CU.
__global__ __launch_bounds__(256) void k_mfma_gate(const unsigned short* __restrict__ Ab,
                                                   const float* __restrict__ Af,
                                                   const unsigned short* __restrict__ Wt,
                                                   const float* __restrict__ bg,
                                                   float* __restrict__ out) {
    __shared__ unsigned short wl[128 * 264];
    const int tid = threadIdx.x;
#pragma unroll
    for (int j = tid; j < 4096; j += 256) {       // 4096 = 128 rows x 32 short8
        const int row = j >> 5, c8 = j & 31;
        *(short8*)(wl + row * 264 + c8 * 8) = *(const short8*)(Wt + row * 256 + c8 * 8);
    }
    __syncthreads();

    const int wv = tid >> 6;
    const int ln = tid & 63;
    const int l16 = ln & 15;
    const int qd = ln >> 4;
    const int rowb = blockIdx.x * 64 + wv * 16;
    const long arow = rowb + l16;
    const int kq = qd * 8;

    f32x4 acc[8];
#pragma unroll
    for (int i = 0; i < 8; ++i) acc[i] = (f32x4){0.f, 0.f, 0.f, 0.f};

    {
        const unsigned short* ap = Ab + arow * 128 + kq;
#pragma unroll
        for (int kc = 0; kc < 4; ++kc) {
            const short8 a = *(const short8*)(ap + kc * 32);
#pragma unroll
            for (int nt = 0; nt < 8; ++nt) {
                const short8 b = *(const short8*)(wl + (nt * 16 + l16) * 264 + kc * 32 + kq);
                acc[nt] = __builtin_amdgcn_mfma_f32_16x16x32_bf16(a, b, acc[nt], 0, 0, 0);
            }
        }
    }
    {
        const bool valid = arow < NN;
        const float* fp = Af + arow * 128 + kq;
#pragma unroll
        for (int kc = 0; kc < 4; ++kc) {
            short8 a = (short8){0, 0, 0, 0, 0, 0, 0, 0};
            if (valid) {
                const float4 f0 = *(const float4*)(fp + kc * 32);
                const float4 f1 = *(const float4*)(fp + kc * 32 + 4);
                a[0] = (short)f2b(clip100(f0.x));
                a[1] = (short)f2b(clip100(f0.y));
                a[2] = (short)f2b(clip100(f0.z));
                a[3] = (short)f2b(clip100(f0.w));
                a[4] = (short)f2b(clip100(f1.x));
                a[5] = (short)f2b(clip100(f1.y));
                a[6] = (short)f2b(clip100(f1.z));
                a[7] = (short)f2b(clip100(f1.w));
            }
#pragma unroll
            for (int nt = 0; nt < 8; ++nt) {
                const short8 b = *(const short8*)(wl + (nt * 16 + l16) * 264 + 128 + kc * 32 + kq);
                acc[nt] = __builtin_amdgcn_mfma_f32_16x16x32_bf16(a, b, acc[nt], 0, 0, 0);
            }
        }
    }

    const int r0 = rowb + qd * 4;
#pragma unroll
    for (int nt = 0; nt < 8; ++nt) {
        const int col = nt * 16 + l16;
        const float bgv = bg[col];
#pragma unroll
        for (int r = 0; r < 4; ++r) {
            const int row = r0 + r;
            if (row < NN) {
                const float g = 1.f / (1.f + __expf(-(acc[nt][r] + bgv)));
                out[(long)row * 128 + col] = b2f(Ab[(long)row * 128 + col]) * g;
            }
        }
    }
}

// ---------------- fused aggregation (bf16 scaled messages, 4x MLP unroll) ----
template <bool RES, bool WF32>
__global__ __launch_bounds__(256) void k_aggr(const unsigned int* __restrict__ As2,
                                              float* __restrict__ Bf,
                                              unsigned short* __restrict__ Bb,
                                              const int* __restrict__ rowptr,
                                              const int* __restrict__ esrc,
                                              const float* __restrict__ dinv,
                                              const float* __restrict__ bias,
                                              const float* __restrict__ x) {
    const int d = (blockIdx.x * 256 + threadIdx.x) >> 6;
    if (d >= NN) return;
    const int lane = threadIdx.x & 63;
    const float dd = dinv[d];

    const unsigned int u = As2[(long)d * 64 + lane];  // self term
    float2 acc;
    acc.x = blo(u);
    acc.y = bhi(u);

    const int beg = rowptr[d];
    const int end = rowptr[d + 1];
    int i = beg;
    for (; i + 4 <= end; i += 4) {
        const int s0 = esrc[i + 0];
        const int s1 = esrc[i + 1];
        const int s2 = esrc[i + 2];
        const int s3 = esrc[i + 3];
        const unsigned int v0 = As2[(long)s0 * 64 + lane];
        const unsigned int v1 = As2[(long)s1 * 64 + lane];
        const unsigned int v2 = As2[(long)s2 * 64 + lane];
        const unsigned int v3 = As2[(long)s3 * 64 + lane];
        acc.x += (blo(v0) + blo(v1)) + (blo(v2) + blo(v3));
        acc.y += (bhi(v0) + bhi(v1)) + (bhi(v2) + bhi(v3));
    }
    for (; i < end; ++i) {
        const unsigned int v = As2[(long)esrc[i] * 64 + lane];
        acc.x += blo(v);
        acc.y += bhi(v);
    }

    const float2 bv = ((const float2*)bias)[lane];
    acc.x = fmaxf(fmaf(acc.x, dd, bv.x), 0.f);
    acc.y = fmaxf(fmaf(acc.y, dd, bv.y), 0.f);
    if (RES) {
        const float2 xv = ((const float2*)x)[(long)d * 64 + lane];
        acc.x += clip100(xv.x);
        acc.y += clip100(xv.y);
    }
    if (WF32) ((float2*)Bf)[(long)d * 64 + lane] = acc;
    const unsigned int pack = (unsigned int)f2b(acc.x) | ((unsigned int)f2b(acc.y) << 16);
    ((unsigned int*)Bb)[(long)d * 64 + lane] = pack;
}

// ---------------- launch ----------------
extern "C" void kernel_launch(void* const* d_in, const int* in_sizes, int n_in,
                              void* d_out, int out_size, void* d_ws, size_t ws_size,
                              hipStream_t stream) {
    const float* x  = (const float*)d_in[0];
    const int*  eix = (const int*)d_in[1];
    const float* W1 = (const float*)d_in[2];
    const float* b1 = (const float*)d_in[3];
    const float* W2 = (const float*)d_in[4];
    const float* b2 = (const float*)d_in[5];
    const float* Wg = (const float*)d_in[6];
    const float* bg = (const float*)d_in[7];
    float* out = (float*)d_out;

    char* ws = (char*)d_ws;
    unsigned short* As   = (unsigned short*)ws;                     // 12,812,288 B
    unsigned short* hb   = (unsigned short*)(ws + 12812288);        // 12,812,288 B
    unsigned short* Wt1  = (unsigned short*)(ws + 25624576);        // 32,768 B
    unsigned short* Wt2  = (unsigned short*)(ws + 25657344);        // 32,768 B
    unsigned short* Wgt  = (unsigned short*)(ws + 25690112);        // 65,536 B
    int*   cnt    = (int*)(ws + 25755648);                          // 200,704 B
    int*   rowptr = (int*)(ws + 25956352);                          // 200,704 B
    float* dinv   = (float*)(ws + 26157056);                        // 200,704 B
    int*   bsum   = (int*)(ws + 26357760);                          // 4,096 B
    int*   bbase  = (int*)(ws + 26361856);                          // 4,096 B
    int*   esrc   = (int*)(ws + 26365952);                          // 3,200,000 B

    const int ggrid = MPAD / 64;  // 782
    dim3 blk(256);

    // weight conversion (also zeroes cnt), then CSR + normalization
    k_cvtw<<<256, blk, 0, stream>>>(W1, W2, Wg, Wt1, Wt2, Wgt, cnt);
    k_hist<<<NPART * NCHUNK, blk, 0, stream>>>(eix, cnt);
    k_bsum<<<NBLK, blk, 0, stream>>>(cnt, bsum);
    k_scanb<<<1, blk, 0, stream>>>(bsum, bbase, rowptr);
    k_scan2<<<NBLK, blk, 0, stream>>>(cnt, bbase, rowptr, dinv);
    k_fill<<<NPART * NCHUNK, blk, 0, stream>>>(eix, cnt, esrc);

    // layer 1: As = bf16((clip(x)@W1) * dinv) ; h1b = bf16(relu(dinv*ΣAs + b1))
    k_mfma_lds<false><<<ggrid, blk, 0, stream>>>(nullptr, x, Wt1, As, dinv);
    k_aggr<false, false><<<(NN * 64 + 255) / 256, blk, 0, stream>>>(
        (const unsigned int*)As, nullptr, hb, rowptr, esrc, dinv, b1, nullptr);

    // layer 2: As = bf16((h1b@W2) * dinv) ; hb = bf16(relu(dinv*ΣAs + b2) + clip(x))
    k_mfma_lds<true><<<ggrid, blk, 0, stream>>>(hb, nullptr, Wt2, As, dinv);
    k_aggr<true, false><<<(NN * 64 + 255) / 256, blk, 0, stream>>>(
        (const unsigned int*)As, nullptr, hb, rowptr, esrc, dinv, b2, x);

    // gate: G = [hb | clip(x)] @ Wgt (K=256) ; out = b2f(hb) * sigmoid(G + bg)
    k_mfma_gate<<<ggrid, blk, 0, stream>>>(hb, x, Wgt, bg, out);
}